// Round 8
// baseline (454.524 us; speedup 1.0000x reference)
//
#include <hip/hip_runtime.h>

#define DIM 64
#define KC 512
#define BLK 256          // 4 waves per block
#define PT 2             // 2 A-tiles (16 points each) per wave -> 32 points/wave
#define CG 32            // centroids per LDS group (16 groups)
#define NT (CG / 16)     // 2 centroid tiles per group
#define NGRP (KC / CG)   // 16 groups

// Margin on v' scale (R7-proven absmax=0 with identical numerics):
//   6-MFMA hi/lo scheme error <= ~3.5e-4; fmac combine <= ~1.5e-5;
//   tile-id packing: 2 cands x 32 ulp(|v'|<128) <= ~1.0e-3
#define MARGINH 2.0e-3f
#define SCALE_LO 4.8828125e-4f   // 2^-11

typedef _Float16 half8   __attribute__((ext_vector_type(8)));
typedef float    floatx4 __attribute__((ext_vector_type(4)));

// Single fused kernel. R0-R7 established: main-loop duration is ~invariant
// (136-158 us) across occupancy (38->69%), delivery (LDS/global), PT (1-4),
// and VALU count -- ~75% of per-SIMD cycles are stalls insensitive to all
// source-level levers. Meanwhile total-minus-main was a CONSTANT ~155 us:
// 3 serialized dispatches (prep -> main -> rescan) + rescan's 128KB-per-block
// LDS staging. This round eliminates the pipeline: prep is recomputed
// per-block (c is 128 KB, L2-resident; ||c||^2 in R1 op order bit-identical),
// B-frags are built in-block per group (inverted thread map -> linear
// conflict-free ds_writes), and uncertified points are rescanned IN-WAVE
// (exact fp32, op order identical to the validated rescan kernel, c read
// straight from L2). One dispatch, no atomics, no workspace.
__global__ __launch_bounds__(BLK)
__attribute__((amdgpu_waves_per_eu(2)))
void kmeans_fused(const float* __restrict__ x, const float* __restrict__ c,
                  int* __restrict__ out, int n)
{
    __shared__ _Float16 shH[2][NT * 2 * 64 * 8];   // 2 x 4 KB ping-pong (hi)
    __shared__ _Float16 shL[2][NT * 2 * 64 * 8];   // 2 x 4 KB ping-pong (lo)
    __shared__ float    s_negh[KC];                // 2 KB  (-c2/2, cert path)
    __shared__ float    s_sc2[KC];                 // 2 KB  (exact c2, rescan)

    const int tid  = threadIdx.x;
    const int wave = tid >> 6;
    const int lane = tid & 63;
    const int nidx = lane & 15;
    const int quad = lane >> 4;

    const long jobBase = ((long)blockIdx.x * 4 + wave) * (PT * 16);

    // ---- prologue A: exact ||c||^2, R1 op order (2 centroids per thread) ----
    #pragma unroll
    for (int kk = 0; kk < 2; ++kk) {
        const int k = kk * BLK + tid;
        const float* crow = c + (long)k * DIM;
        float s0 = 0.f, s1 = 0.f, s2 = 0.f, s3 = 0.f;
        #pragma unroll
        for (int d = 0; d < DIM; d += 4) {
            s0 = fmaf(crow[d + 0], crow[d + 0], s0);
            s1 = fmaf(crow[d + 1], crow[d + 1], s1);
            s2 = fmaf(crow[d + 2], crow[d + 2], s2);
            s3 = fmaf(crow[d + 3], crow[d + 3], s3);
        }
        const float s = (s0 + s1) + (s2 + s3);
        s_sc2[k]  = s;            // exact, for in-wave rescan
        s_negh[k] = -0.5f * s;    // exact (x0.5), MFMA C-operand
    }

    // ---- inverted staging map: thread tid owns LDS halves [tid*8 .. tid*8+7]
    // pos/8 = (tt*2+ch)*64 + q*16 + ni == tid  with
    //   tt=(tid>>7)&1, ch=(tid>>6)&1, q=(tid>>4)&3, ni=tid&15
    // -> reads c[group*32 + tt*16+ni][ch*32+q*8 .. +7]; ds_writes are linear
    //    (16 B per lane at byte tid*16): bank-conflict-free.
    const int m_tt = (tid >> 7) & 1;
    const int m_ch = (tid >> 6) & 1;
    const int m_q  = (tid >> 4) & 3;
    const int m_ni = tid & 15;
    const int crd  = (m_tt * 16 + m_ni) * DIM + m_ch * 32 + m_q * 8; // float offset in group

    // conversion identical to the validated prep kernel
    auto cvt_store = [&](int buf, const float4& v0, const float4& v1) {
        const float fs[8] = {v0.x, v0.y, v0.z, v0.w, v1.x, v1.y, v1.z, v1.w};
        half8 hh, ll;
        #pragma unroll
        for (int j = 0; j < 8; ++j) {
            const _Float16 h = (_Float16)fs[j];
            hh[j] = h;
            ll[j] = (_Float16)((fs[j] - (float)h) * 2048.0f);
        }
        *(half8*)&shH[buf][tid * 8] = hh;
        *(half8*)&shL[buf][tid * 8] = ll;
    };

    // ---- prologue B: stage group 0 into buffer 0 ----
    {
        const float* src = c + crd;                 // group 0
        const float4 v0 = *(const float4*)src;
        const float4 v1 = *(const float4*)(src + 4);
        cvt_store(0, v0, v1);
    }

    // ---- A fragments (hi + lo*2048), R0-validated construction ----
    half8 ah[PT][2], al[PT][2];
    #pragma unroll
    for (int pt = 0; pt < PT; ++pt) {
        long row = jobBase + pt * 16 + nidx;
        if (row > (long)n - 1) row = (long)n - 1;
        #pragma unroll
        for (int ch = 0; ch < 2; ++ch) {
            const float* xp = x + row * DIM + ch * 32 + quad * 8;
            float4 v0 = *(const float4*)xp;
            float4 v1 = *(const float4*)(xp + 4);
            float fs[8] = {v0.x, v0.y, v0.z, v0.w, v1.x, v1.y, v1.z, v1.w};
            #pragma unroll
            for (int j = 0; j < 8; ++j) {
                _Float16 h = (_Float16)fs[j];
                ah[pt][ch][j] = h;
                al[pt][ch][j] = (_Float16)((fs[j] - (float)h) * 2048.0f);
            }
        }
    }

    // packed argmax state over v' = dot - c2/2 (low 5 mantissa bits = tile id)
    float best[PT][4], sec[PT][4];
    #pragma unroll
    for (int pt = 0; pt < PT; ++pt)
        #pragma unroll
        for (int r = 0; r < 4; ++r) {
            best[pt][r] = -3.402823466e38f;
            sec[pt][r]  = -3.402823466e38f;
        }

    const floatx4 ZERO = {0.f, 0.f, 0.f, 0.f};

    __syncthreads();   // s_sc2/s_negh + group-0 frags visible

    for (int g = 0; g < NGRP; ++g) {
        const int cur = g & 1;
        // issue next group's c loads now; convert+write after compute
        float4 nv0, nv1;
        if (g + 1 < NGRP) {
            const float* src = c + (long)(g + 1) * CG * DIM + crd;
            nv0 = *(const float4*)src;
            nv1 = *(const float4*)(src + 4);
        }

        #pragma unroll
        for (int t = 0; t < NT; ++t) {
            const half8 bh0 = *(const half8*)&shH[cur][((t * 2 + 0) * 64 + lane) * 8];
            const half8 bh1 = *(const half8*)&shH[cur][((t * 2 + 1) * 64 + lane) * 8];
            const half8 bl0 = *(const half8*)&shL[cur][((t * 2 + 0) * 64 + lane) * 8];
            const half8 bl1 = *(const half8*)&shL[cur][((t * 2 + 1) * 64 + lane) * 8];
            const int   T5    = g * NT + t;                 // 5-bit global tile id
            const float ng    = s_negh[T5 * 16 + nidx];     // prefolded -c2/2
            const floatx4 cinit = {ng, ng, ng, ng};
            #pragma unroll
            for (int pt = 0; pt < PT; ++pt) {
                floatx4 am, ac;
                am = __builtin_amdgcn_mfma_f32_16x16x32_f16(ah[pt][0], bh0, cinit, 0, 0, 0);
                am = __builtin_amdgcn_mfma_f32_16x16x32_f16(ah[pt][1], bh1, am, 0, 0, 0);
                ac = __builtin_amdgcn_mfma_f32_16x16x32_f16(ah[pt][0], bl0, ZERO, 0, 0, 0);
                ac = __builtin_amdgcn_mfma_f32_16x16x32_f16(ah[pt][1], bl1, ac, 0, 0, 0);
                ac = __builtin_amdgcn_mfma_f32_16x16x32_f16(al[pt][0], bh0, ac, 0, 0, 0);
                ac = __builtin_amdgcn_mfma_f32_16x16x32_f16(al[pt][1], bh1, ac, 0, 0, 0);
                #pragma unroll
                for (int r = 0; r < 4; ++r) {
                    const float vv = fmaf(ac[r], SCALE_LO, am[r]);   // one fmac combine
                    const float vp = __uint_as_float(
                        (__float_as_uint(vv) & 0xFFFFFFE0u) | (unsigned)T5);
                    sec[pt][r]  = __builtin_amdgcn_fmed3f(sec[pt][r], vp, best[pt][r]);
                    best[pt][r] = fmaxf(best[pt][r], vp);
                }
            }
        }

        if (g + 1 < NGRP) {
            // write buf^1 (read only after the barrier; buf^1 readers of the
            // PREVIOUS group were released by the barrier at end of g-1)
            cvt_store(cur ^ 1, nv0, nv1);
            __syncthreads();
        }
    }

    // unpack indices, then butterfly over the 16 n-lanes of each quad
    int bidx[PT][4];
    #pragma unroll
    for (int pt = 0; pt < PT; ++pt)
        #pragma unroll
        for (int r = 0; r < 4; ++r)
            bidx[pt][r] = (int)((__float_as_uint(best[pt][r]) & 31u) << 4) + nidx;

    #pragma unroll
    for (int off = 1; off < 16; off <<= 1) {
        #pragma unroll
        for (int pt = 0; pt < PT; ++pt)
            #pragma unroll
            for (int r = 0; r < 4; ++r) {
                const float ob = __shfl_xor(best[pt][r], off, 64);
                const int   oi = __shfl_xor(bidx[pt][r], off, 64);
                const float os = __shfl_xor(sec[pt][r],  off, 64);
                const bool take = (ob > best[pt][r]) ||
                                  (ob == best[pt][r] && oi < bidx[pt][r]);
                const float loser = take ? best[pt][r] : ob;
                sec[pt][r]  = fmaxf(fmaxf(sec[pt][r], os), loser);
                best[pt][r] = take ? ob : best[pt][r];
                bidx[pt][r] = take ? oi : bidx[pt][r];
            }
    }

    // write: lanes nidx 0..7 own (pt_w = nidx>>2, r_w = nidx&3) at row quad*4+r_w
    const int pt_w = nidx >> 2;    // 0..1 used; nidx >= 8 idle
    const int r_w  = nidx & 3;
    float b = 0.f, s = 0.f; int bi = 0;
    #pragma unroll
    for (int pt = 0; pt < PT; ++pt)
        #pragma unroll
        for (int r = 0; r < 4; ++r) {
            const bool m = (pt == pt_w) && (r == r_w);
            b  = m ? best[pt][r] : b;
            s  = m ? sec[pt][r]  : s;
            bi = m ? bidx[pt][r] : bi;
        }
    const long p = jobBase + (long)pt_w * 16 + quad * 4 + r_w;

    const bool valid = (nidx < 8) && (p < n);
    if (valid) out[p] = bi;                          // exact when certified
    const bool need  = valid && !(b - s > MARGINH);  // uncertified -> in-wave rescan

    // ---- in-wave exact rescan (op order identical to the validated rescan
    // kernel; c read straight from L2, c2 from s_sc2) ----
    unsigned long long mm = __ballot(need);
    while (mm) {
        const int ol = (int)(__ffsll(mm) - 1);
        mm &= (mm - 1ull);
        const int pp = __builtin_amdgcn_readfirstlane(__shfl((int)p, ol, 64));

        const float* xrow = x + (long)pp * DIM;      // SGPR base -> s_loads
        float x20 = 0.f, x21 = 0.f, x22 = 0.f, x23 = 0.f;
        #pragma unroll
        for (int d = 0; d < DIM; d += 4) {
            x20 = fmaf(xrow[d + 0], xrow[d + 0], x20);
            x21 = fmaf(xrow[d + 1], xrow[d + 1], x21);
            x22 = fmaf(xrow[d + 2], xrow[d + 2], x22);
            x23 = fmaf(xrow[d + 3], xrow[d + 3], x23);
        }
        const float x2 = (x20 + x21) + (x22 + x23);

        float bb = 3.402823466e38f; int bbi = 0x7fffffff;
        #pragma unroll
        for (int kk2 = 0; kk2 < 8; ++kk2) {
            const int k = kk2 * 64 + lane;           // distinct ks; lex reduce handles order
            const float* crow = c + (long)k * DIM;
            float d0 = 0.f, d1 = 0.f, d2a = 0.f, d3 = 0.f;
            #pragma unroll
            for (int d4 = 0; d4 < 16; ++d4) {
                const float4 q4 = *(const float4*)(crow + d4 * 4);  // L2-hot
                d0  = fmaf(q4.x, xrow[4 * d4 + 0], d0);
                d1  = fmaf(q4.y, xrow[4 * d4 + 1], d1);
                d2a = fmaf(q4.z, xrow[4 * d4 + 2], d2a);
                d3  = fmaf(q4.w, xrow[4 * d4 + 3], d3);
            }
            const float dot = (d0 + d1) + (d2a + d3);
            float d2v = (x2 + s_sc2[k]) - 2.0f * dot;
            d2v = fmaxf(d2v, 0.0f);
            const bool l2 = (d2v < bb) || (d2v == bb && k < bbi);
            bb  = l2 ? d2v : bb;
            bbi = l2 ? k   : bbi;
        }
        #pragma unroll
        for (int off = 1; off < 64; off <<= 1) {
            const float ob = __shfl_xor(bb, off, 64);
            const int   oi = __shfl_xor(bbi, off, 64);
            const bool take = (ob < bb) || (ob == bb && oi < bbi);
            bb  = take ? ob : bb;
            bbi = take ? oi : bbi;
        }
        if (lane == 0) out[pp] = bbi;                // exact overwrite
    }
}

extern "C" void kernel_launch(void* const* d_in, const int* in_sizes, int n_in,
                              void* d_out, int out_size, void* d_ws, size_t ws_size,
                              hipStream_t stream) {
    const float* x = (const float*)d_in[0];   // [N, 64] fp32
    const float* c = (const float*)d_in[1];   // [512, 64] fp32
    int* out = (int*)d_out;                   // [N] int32 labels
    const int n = in_sizes[0] / DIM;

    (void)d_ws; (void)ws_size;                // single fused kernel: no workspace

    const int jobs   = (n + PT * 16 - 1) / (PT * 16);  // 32 points per wave
    const int blocks = (jobs + 3) / 4;                 // 4 waves per block
    kmeans_fused<<<blocks, BLK, 0, stream>>>(x, c, out, n);
}